// Round 10
// baseline (161.684 us; speedup 1.0000x reference)
//
#include <hip/hip_runtime.h>

#define DIM 256
#define NA 16
#define NE 4
#define KTOT 288   // 16 atoms + 256 latent + 16 zero pad
#define KC 96      // K per third

typedef __attribute__((ext_vector_type(8))) short short8;
typedef __attribute__((ext_vector_type(4))) float f32x4;

static __device__ __forceinline__ ushort f2bf(float f) {
  union { float f; unsigned int u; } v; v.f = f;
  unsigned int r = (v.u + 0x7FFFu + ((v.u >> 16) & 1u)) >> 16;
  return (ushort)r;
}

static __device__ __forceinline__ float bf2f(ushort s) {
  union { unsigned int u; float f; } v; v.u = ((unsigned int)s) << 16;
  return v.f;
}

static __device__ __forceinline__ unsigned cvtpk(float lo, float hi) {
  unsigned r;
  asm("v_cvt_pk_bf16_f32 %0, %1, %2" : "=v"(r) : "v"(lo), "v"(hi));
  return r;
}

// async global->LDS DMA, 16B per lane; lds dest must be wave-uniform (HW adds lane*16)
static __device__ __forceinline__ void gll16(const void* g, void* l) {
  __builtin_amdgcn_global_load_lds((const __attribute__((address_space(1))) void*)g,
                                   (__attribute__((address_space(3))) void*)l, 16, 0, 0);
}

// ---------------- prep 1: h = relu(latent@W1+b1)@W2+b2 ; build G = [atoms|h|0] bf16
__global__ __launch_bounds__(256) void prep_h_kernel(
    const float* __restrict__ latent, const float* __restrict__ atoms,
    const float* __restrict__ W1, const float* __restrict__ b1,
    const float* __restrict__ W2, const float* __restrict__ b2,
    float* __restrict__ h_out, ushort* __restrict__ G_out) {
  __shared__ float lat[8][DIM];
  __shared__ float t1[8][DIM];
  const int b = blockIdx.x >> 5, i0 = (blockIdx.x & 31) * 8;
  const int k = threadIdx.x;
  #pragma unroll
  for (int r = 0; r < 8; ++r) lat[r][k] = latent[(b*256 + i0 + r) * DIM + k];
  __syncthreads();
  float acc[8];
  #pragma unroll
  for (int r = 0; r < 8; ++r) acc[r] = b1[k];
  for (int c = 0; c < DIM; c += 4) {
    float w0 = W1[(c+0)*DIM + k], w1 = W1[(c+1)*DIM + k];
    float w2 = W1[(c+2)*DIM + k], w3 = W1[(c+3)*DIM + k];
    #pragma unroll
    for (int r = 0; r < 8; ++r) {
      const float4 l4 = *reinterpret_cast<const float4*>(&lat[r][c]);
      acc[r] += l4.x*w0 + l4.y*w1 + l4.z*w2 + l4.w*w3;
    }
  }
  #pragma unroll
  for (int r = 0; r < 8; ++r) t1[r][k] = fmaxf(acc[r], 0.f);
  __syncthreads();
  #pragma unroll
  for (int r = 0; r < 8; ++r) acc[r] = b2[k];
  for (int c = 0; c < DIM; c += 4) {
    float w0 = W2[(c+0)*DIM + k], w1 = W2[(c+1)*DIM + k];
    float w2 = W2[(c+2)*DIM + k], w3 = W2[(c+3)*DIM + k];
    #pragma unroll
    for (int r = 0; r < 8; ++r) {
      const float4 l4 = *reinterpret_cast<const float4*>(&t1[r][c]);
      acc[r] += l4.x*w0 + l4.y*w1 + l4.z*w2 + l4.w*w3;
    }
  }
  #pragma unroll
  for (int r = 0; r < 8; ++r) {
    int row = b*256 + i0 + r;
    h_out[row*DIM + k] = acc[r];
    G_out[row*KTOT + NA + k] = f2bf(acc[r]);
  }
  if (k < NA) {
    #pragma unroll
    for (int r = 0; r < 8; ++r) {
      int row = b*256 + i0 + r;
      G_out[row*KTOT + k] = f2bf(atoms[row*NA + k]);
      G_out[row*KTOT + 272 + k] = 0;
    }
  }
}

// ---------------- prep 2: W3T[k][c] = bf16(W3[1+c][k]) zero-padded to 288
__global__ __launch_bounds__(256) void prep_w3t_kernel(
    const float* __restrict__ W3, ushort* __restrict__ W3T) {
  const int kk = blockIdx.x, c = threadIdx.x;
  W3T[kk*KTOT + c] = (c < 272) ? f2bf(W3[(1+c)*DIM + kk]) : (ushort)0;
  if (c < 32) {
    int c2 = 256 + c;
    W3T[kk*KTOT + c2] = (c2 < 272) ? f2bf(W3[(1+c2)*DIM + kk]) : (ushort)0;
  }
}

// ---------------- main: per (b,i,jh) workgroup of 256 threads; SYMMETRY + 2 WG/CU
// Z[i,j,n] = sum_c W3T[n,c]*G[i,c]*G[j,c], symmetric in i<->j.
// WG (i,jh) handles j-tiles {jt0+jh, jt0+jh+2, ...} (parity split of j>=i tiles).
// LDS ~76KB -> 2 WGs/CU co-resident: prologue/barrier/DMA latencies overlap.
// Direct write out[i][j] for j>=i; mirror out[j][i] for j>i (each elem once).
__global__ __attribute__((amdgpu_flat_work_group_size(256,256), amdgpu_waves_per_eu(2,2)))
void edge_main_kernel(
    const float* __restrict__ positions, const float* __restrict__ atoms,
    const float* __restrict__ W3, const float* __restrict__ b3,
    const float* __restrict__ W4, const float* __restrict__ b4,
    const float* __restrict__ h_ws, const ushort* __restrict__ G,
    const ushort* __restrict__ W3T, float* __restrict__ out) {
  __shared__ union UU {
    char slab[24576];             // single-buffered G j-half-slab (8 tiles x 3KB)
    float partial[4][128][4];     // epilogue partials (8KB), used after final barrier
  } u;
  __shared__ char af_lds[49152];  // af slab for current K-third (48KB)
  __shared__ float g_lds[KTOT];
  __shared__ float dist_lds[256];

  const int bid = blockIdx.x;
  const int b = bid >> 9, rem = bid & 511;
  const int i = rem >> 1, jh = rem & 1;
  const int tid = threadIdx.x;
  const int lane = tid & 63, w = tid >> 6;   // w = wn (n-quadrant, 64 cols each)
  const int c15 = lane & 15, hi = lane >> 4;
  const int rowbase = b*256 + i;
  const int bbase = b*256;

  const int jt0 = i >> 4;                    // first j-tile
  const int NT  = 16 - jt0;                  // j-tiles in symmetric range (1..16)
  const int jcount = (NT - jh + 1) >> 1;     // this WG's tiles: jt0+jh, +2, ... (0..8)
  const int nst = jcount * 12;               // subtiles in slab per K-third

  // prologue loads: g (288), dist (256)
  g_lds[tid] = (tid < NA) ? atoms[rowbase*NA + tid] : h_ws[rowbase*DIM + (tid - NA)];
  if (tid < 32) {
    int t2 = 256 + tid;
    g_lds[t2] = (t2 < 272) ? h_ws[rowbase*DIM + (t2 - NA)] : 0.f;
  }
  {
    const float* pi = &positions[rowbase*3];
    const float* pj = &positions[(bbase + tid)*3];
    float dx = pi[0]-pj[0], dy = pi[1]-pj[1], dz = pi[2]-pj[2];
    float d2 = dx*dx + dy*dy + dz*dz;
    dist_lds[tid] = d2 > 0.f ? sqrtf(d2) : 0.f;
  }

  // ---- async stage of this WG's j-half-slab for K-third t3 (single buffer)
  auto stage = [&](int t3) {
    #pragma unroll
    for (int ch = 0; ch < 6; ++ch) {
      int st0 = ch*16 + w*4;            // wave-uniform 4-subtile group
      if (st0 >= nst) break;            // wave-uniform early-out
      int st = st0 + hi;
      int tt = st / 12, ks = st - tt*12;
      int row = bbase + (jt0 + jh + 2*tt)*16 + c15;
      const ushort* src = &G[(size_t)row * KTOT + t3*KC + ks*8];
      gll16(src, u.slab + st0*256);     // uniform dest; lane data at +lane*16
    }
  };

  f32x4 acc[4][8];
  #pragma unroll
  for (int nt = 0; nt < 4; ++nt)
    #pragma unroll
    for (int t = 0; t < 8; ++t) { acc[nt][t].x=0.f; acc[nt][t].y=0.f; acc[nt][t].z=0.f; acc[nt][t].w=0.f; }

  stage(0);

  #pragma unroll
  for (int t3 = 0; t3 < 3; ++t3) {
    // ---- build af[t3] cooperatively into LDS: af[n][c] = bf16(g[c]*W3T[n][c])
    // overlaps the in-flight stage(t3) DMA; 12 spans of 16B per thread
    #pragma unroll
    for (int s = 0; s < 12; ++s) {
      int id = s*256 + tid;
      int st2 = id >> 4, c15r = id & 15;
      int ntile = st2 / 12, ks = st2 - ntile*12;
      int n = ntile*16 + c15r;
      union { ushort us[8]; short8 s8; } wv;
      wv.s8 = *reinterpret_cast<const short8*>(&W3T[(size_t)n*KTOT + t3*KC + ks*8]);
      const float* gp = &g_lds[t3*KC + ks*8];
      float4 ga = *reinterpret_cast<const float4*>(gp);
      float4 gb = *reinterpret_cast<const float4*>(gp + 4);
      union { unsigned uu[4]; short8 s8; } pk;
      pk.uu[0] = cvtpk(bf2f(wv.us[0])*ga.x, bf2f(wv.us[1])*ga.y);
      pk.uu[1] = cvtpk(bf2f(wv.us[2])*ga.z, bf2f(wv.us[3])*ga.w);
      pk.uu[2] = cvtpk(bf2f(wv.us[4])*gb.x, bf2f(wv.us[5])*gb.y);
      pk.uu[3] = cvtpk(bf2f(wv.us[6])*gb.z, bf2f(wv.us[7])*gb.w);
      *reinterpret_cast<short8*>(&af_lds[st2*256 + c15r*16]) = pk.s8;
    }
    __syncthreads();   // stage(t3) DMA drained + af[t3] + (t3==0: g/dist) visible
    // ---- MFMA over this third (guarded compile-time-unrolled t loop)
    #pragma unroll
    for (int kc2 = 0; kc2 < 3; ++kc2) {
      short8 afr[4];
      #pragma unroll
      for (int nt = 0; nt < 4; ++nt)
        afr[nt] = *reinterpret_cast<const short8*>(
            &af_lds[((w*4 + nt)*12 + kc2*4)*256 + lane*16]);
      #pragma unroll
      for (int t = 0; t < 8; ++t) {
        if (t < jcount) {              // WG-uniform guard
          short8 bb = *reinterpret_cast<const short8*>(
              u.slab + (t*12 + kc2*4)*256 + lane*16);
          acc[0][t] = __builtin_amdgcn_mfma_f32_16x16x32_bf16(afr[0], bb, acc[0][t], 0, 0, 0);
          acc[1][t] = __builtin_amdgcn_mfma_f32_16x16x32_bf16(afr[1], bb, acc[1][t], 0, 0, 0);
          acc[2][t] = __builtin_amdgcn_mfma_f32_16x16x32_bf16(afr[2], bb, acc[2][t], 0, 0, 0);
          acc[3][t] = __builtin_amdgcn_mfma_f32_16x16x32_bf16(afr[3], bb, acc[3][t], 0, 0, 0);
        }
      }
    }
    __syncthreads();   // slab+af readers done; safe to re-stage / rebuild / epilogue
    if (t3 < 2) stage(t3 + 1);
  }

  __builtin_amdgcn_sched_barrier(0);   // keep epilogue loads OUT of the K-loop region

  // ---- epilogue: z = acc + dist*w30 + b3 ; relu ; second layer (256 -> 4)
  float b3v[4][4], w30v[4][4]; float4 w4v[4][4];
  #pragma unroll
  for (int nt = 0; nt < 4; ++nt)
    #pragma unroll
    for (int r = 0; r < 4; ++r) {
      int n = w*64 + nt*16 + hi*4 + r;
      b3v[nt][r]  = b3[n];
      w30v[nt][r] = W3[n];                 // W3 row 0 = dist weights
      w4v[nt][r]  = *reinterpret_cast<const float4*>(&W4[n*4]);
    }
  #pragma unroll
  for (int t = 0; t < 8; ++t) {
    if (t < jcount) {
      int j = (jt0 + jh + 2*t)*16 + c15;
      float d = dist_lds[j];
      float4 pe; pe.x=0.f; pe.y=0.f; pe.z=0.f; pe.w=0.f;
      #pragma unroll
      for (int nt = 0; nt < 4; ++nt)
        #pragma unroll
        for (int r = 0; r < 4; ++r) {
          float z  = acc[nt][t][r] + d*w30v[nt][r] + b3v[nt][r];
          float rz = fmaxf(z, 0.f);
          pe.x += rz*w4v[nt][r].x; pe.y += rz*w4v[nt][r].y;
          pe.z += rz*w4v[nt][r].z; pe.w += rz*w4v[nt][r].w;
        }
      pe.x += __shfl_xor(pe.x, 16); pe.y += __shfl_xor(pe.y, 16);
      pe.z += __shfl_xor(pe.z, 16); pe.w += __shfl_xor(pe.w, 16);
      pe.x += __shfl_xor(pe.x, 32); pe.y += __shfl_xor(pe.y, 32);
      pe.z += __shfl_xor(pe.z, 32); pe.w += __shfl_xor(pe.w, 32);
      if (hi == 0) *reinterpret_cast<float4*>(&u.partial[w][t*16 + c15][0]) = pe;
    }
  }
  __syncthreads();
  #pragma unroll
  for (int rep = 0; rep < 2; ++rep) {
    int o = rep*256 + tid;
    int jj = o >> 2, e = o & 3, tt = jj >> 4;
    if (tt < jcount) {
      int j = (jt0 + jh + 2*tt)*16 + (jj & 15);
      float v = u.partial[0][jj][e] + u.partial[1][jj][e]
              + u.partial[2][jj][e] + u.partial[3][jj][e] + b4[e];
      if (j >= i) out[((size_t)rowbase*256 + j)*NE + e] = v;            // upper+diag
      if (j > i)  out[((size_t)(bbase + j)*256 + i)*NE + e] = v;        // mirror
    }
  }
}

extern "C" void kernel_launch(void* const* d_in, const int* in_sizes, int n_in,
                              void* d_out, int out_size, void* d_ws, size_t ws_size,
                              hipStream_t stream) {
  const float* latent    = (const float*)d_in[0];
  const float* positions = (const float*)d_in[1];
  const float* atoms     = (const float*)d_in[2];
  const float* W1 = (const float*)d_in[3];
  const float* b1 = (const float*)d_in[4];
  const float* W2 = (const float*)d_in[5];
  const float* b2 = (const float*)d_in[6];
  const float* W3 = (const float*)d_in[7];
  const float* b3 = (const float*)d_in[8];
  const float* W4 = (const float*)d_in[9];
  const float* b4 = (const float*)d_in[10];
  float* out = (float*)d_out;

  char* ws = (char*)d_ws;
  float*  h_ws   = (float*)ws;                          // 8*256*256*4   = 2,097,152 B
  ushort* G_ws   = (ushort*)(ws + 2097152);             // 8*256*288*2   = 1,179,648 B
  ushort* W3T_ws = (ushort*)(ws + 2097152 + 1179648);   // 256*288*2     =   147,456 B

  hipLaunchKernelGGL(prep_h_kernel, dim3(256), dim3(256), 0, stream,
                     latent, atoms, W1, b1, W2, b2, h_ws, G_ws);
  hipLaunchKernelGGL(prep_w3t_kernel, dim3(256), dim3(256), 0, stream, W3, W3T_ws);
  hipLaunchKernelGGL(edge_main_kernel, dim3(4096), dim3(256), 0, stream,
                     positions, atoms, W3, b3, W4, b4, h_ws, G_ws, W3T_ws, out);
}

// Round 11
// 159.705 us; speedup vs baseline: 1.0124x; 1.0124x over previous
//
#include <hip/hip_runtime.h>

#define DIM 256
#define NA 16
#define NE 4
#define KTOT 288   // 16 atoms + 256 latent + 16 zero pad

typedef __attribute__((ext_vector_type(8))) short short8;
typedef __attribute__((ext_vector_type(4))) float f32x4;

static __device__ __forceinline__ ushort f2bf(float f) {
  union { float f; unsigned int u; } v; v.f = f;
  unsigned int r = (v.u + 0x7FFFu + ((v.u >> 16) & 1u)) >> 16;
  return (ushort)r;
}

static __device__ __forceinline__ float bf2f(ushort s) {
  union { unsigned int u; float f; } v; v.u = ((unsigned int)s) << 16;
  return v.f;
}

static __device__ __forceinline__ unsigned cvtpk(float lo, float hi) {
  unsigned r;
  asm("v_cvt_pk_bf16_f32 %0, %1, %2" : "=v"(r) : "v"(lo), "v"(hi));
  return r;
}

// async global->LDS DMA, 16B per lane; lds dest must be wave-uniform (HW adds lane*16)
static __device__ __forceinline__ void gll16(const void* g, void* l) {
  __builtin_amdgcn_global_load_lds((const __attribute__((address_space(1))) void*)g,
                                   (__attribute__((address_space(3))) void*)l, 16, 0, 0);
}

// ---------------- prep 1: h = relu(latent@W1+b1)@W2+b2 ; build G = [atoms|h|0] bf16
__global__ __launch_bounds__(256) void prep_h_kernel(
    const float* __restrict__ latent, const float* __restrict__ atoms,
    const float* __restrict__ W1, const float* __restrict__ b1,
    const float* __restrict__ W2, const float* __restrict__ b2,
    float* __restrict__ h_out, ushort* __restrict__ G_out) {
  __shared__ float lat[8][DIM];
  __shared__ float t1[8][DIM];
  const int b = blockIdx.x >> 5, i0 = (blockIdx.x & 31) * 8;
  const int k = threadIdx.x;
  #pragma unroll
  for (int r = 0; r < 8; ++r) lat[r][k] = latent[(b*256 + i0 + r) * DIM + k];
  __syncthreads();
  float acc[8];
  #pragma unroll
  for (int r = 0; r < 8; ++r) acc[r] = b1[k];
  for (int c = 0; c < DIM; c += 4) {
    float w0 = W1[(c+0)*DIM + k], w1 = W1[(c+1)*DIM + k];
    float w2 = W1[(c+2)*DIM + k], w3 = W1[(c+3)*DIM + k];
    #pragma unroll
    for (int r = 0; r < 8; ++r) {
      const float4 l4 = *reinterpret_cast<const float4*>(&lat[r][c]);
      acc[r] += l4.x*w0 + l4.y*w1 + l4.z*w2 + l4.w*w3;
    }
  }
  #pragma unroll
  for (int r = 0; r < 8; ++r) t1[r][k] = fmaxf(acc[r], 0.f);
  __syncthreads();
  #pragma unroll
  for (int r = 0; r < 8; ++r) acc[r] = b2[k];
  for (int c = 0; c < DIM; c += 4) {
    float w0 = W2[(c+0)*DIM + k], w1 = W2[(c+1)*DIM + k];
    float w2 = W2[(c+2)*DIM + k], w3 = W2[(c+3)*DIM + k];
    #pragma unroll
    for (int r = 0; r < 8; ++r) {
      const float4 l4 = *reinterpret_cast<const float4*>(&t1[r][c]);
      acc[r] += l4.x*w0 + l4.y*w1 + l4.z*w2 + l4.w*w3;
    }
  }
  #pragma unroll
  for (int r = 0; r < 8; ++r) {
    int row = b*256 + i0 + r;
    h_out[row*DIM + k] = acc[r];
    G_out[row*KTOT + NA + k] = f2bf(acc[r]);
  }
  if (k < NA) {
    #pragma unroll
    for (int r = 0; r < 8; ++r) {
      int row = b*256 + i0 + r;
      G_out[row*KTOT + k] = f2bf(atoms[row*NA + k]);
      G_out[row*KTOT + 272 + k] = 0;
    }
  }
}

// ---------------- prep 2: W3T[k][c] = bf16(W3[1+c][k]) zero-padded to 288
__global__ __launch_bounds__(256) void prep_w3t_kernel(
    const float* __restrict__ W3, ushort* __restrict__ W3T) {
  const int kk = blockIdx.x, c = threadIdx.x;
  W3T[kk*KTOT + c] = (c < 272) ? f2bf(W3[(1+c)*DIM + kk]) : (ushort)0;
  if (c < 32) {
    int c2 = 256 + c;
    W3T[kk*KTOT + c2] = (c2 < 272) ? f2bf(W3[(1+c2)*DIM + kk]) : (ushort)0;
  }
}

// ---------------- main: per (b,i) WG of 512 thr; SYMMETRY + wave-local af +
// 9 x 32c K-chunks, both operands double-buffered, ONE barrier per chunk.
// Z[i,j,n] = sum_c W3T[n,c]*g_i[c]*G[j,c]; WG i does j-tiles >= i's tile.
// af is built by the wave that consumes it (own n-quadrant) -> no build barrier.
__global__ __attribute__((amdgpu_flat_work_group_size(512,512), amdgpu_waves_per_eu(2,2)))
void edge_main_kernel(
    const float* __restrict__ positions, const float* __restrict__ atoms,
    const float* __restrict__ W3, const float* __restrict__ b3,
    const float* __restrict__ W4, const float* __restrict__ b4,
    const float* __restrict__ h_ws, const ushort* __restrict__ G,
    const ushort* __restrict__ W3T, float* __restrict__ out) {
  __shared__ union UU {
    char slabs[2][16384];         // G chunk dbuf: 16 tiles x 1KB each
    float partial[4][256][4];     // epilogue partials (16KB), after final barrier
  } u;
  __shared__ char af_lds[2][16384];  // af chunk dbuf: 16 ntiles x 1KB
  __shared__ float g_lds[KTOT];
  __shared__ float dist_lds[256];

  const int b = blockIdx.x >> 8, i = blockIdx.x & 255;
  const int tid = threadIdx.x;
  const int lane = tid & 63, w = tid >> 6;
  const int wn = w & 3;           // n-quadrant: 64 cols each
  const int wj = w >> 2;          // j-tile parity group
  const int c15 = lane & 15, hi = lane >> 4;
  const int rowbase = b*256 + i;
  const int bbase = b*256;

  const int jt0 = i >> 4;                    // first j-tile
  const int NT  = 16 - jt0;                  // j-tiles in symmetric range (1..16)
  const int tcnt = (NT - wj + 1) >> 1;       // tiles for this wave: wj, wj+2, ...

  // ---- stage G chunk kk: tile t at slabs[kk&1]+t*1024; lane(hi,c15) holds
  // G[jtile*16+c15][kk*32+hi*8 ..+8] — identical mapping to MFMA bb read.
  auto stage = [&](int kk) {
    #pragma unroll
    for (int rep = 0; rep < 2; ++rep) {
      int t = w + rep*8;
      if (t < NT) {     // wave-uniform
        const ushort* src = &G[(size_t)(bbase + (jt0 + t)*16 + c15)*KTOT + kk*32 + hi*8];
        gll16(src, u.slabs[kk & 1] + t*1024);
      }
    }
  };

  // ---- wave-local af build for chunk kk: af[n][c]=bf16(g[c]*W3T[n][c]),
  // n in this wave's quadrant only -> no cross-wave hazard, no barrier.
  auto build_af = [&](int kk) {
    char* dst = af_lds[kk & 1];
    float4 ga = *reinterpret_cast<const float4*>(&g_lds[kk*32 + hi*8]);
    float4 gb = *reinterpret_cast<const float4*>(&g_lds[kk*32 + hi*8 + 4]);
    #pragma unroll
    for (int nt = 0; nt < 4; ++nt) {
      int n = wn*64 + nt*16 + c15;
      union { ushort us[8]; short8 s8; } wv;
      wv.s8 = *reinterpret_cast<const short8*>(&W3T[(size_t)n*KTOT + kk*32 + hi*8]);
      union { unsigned uu[4]; short8 s8; } pk;
      pk.uu[0] = cvtpk(bf2f(wv.us[0])*ga.x, bf2f(wv.us[1])*ga.y);
      pk.uu[1] = cvtpk(bf2f(wv.us[2])*ga.z, bf2f(wv.us[3])*ga.w);
      pk.uu[2] = cvtpk(bf2f(wv.us[4])*gb.x, bf2f(wv.us[5])*gb.y);
      pk.uu[3] = cvtpk(bf2f(wv.us[6])*gb.z, bf2f(wv.us[7])*gb.w);
      *reinterpret_cast<short8*>(&dst[((wn*4 + nt)*4 + hi)*256 + c15*16]) = pk.s8;
    }
  };

  stage(0);
  // prologue: g (288), dist (256)
  if (tid < KTOT)
    g_lds[tid] = (tid < NA) ? atoms[rowbase*NA + tid]
               : (tid < 272 ? h_ws[rowbase*DIM + (tid - NA)] : 0.f);
  if (tid < 256) {
    const float* pi = &positions[rowbase*3];
    const float* pj = &positions[(bbase + tid)*3];
    float dx = pi[0]-pj[0], dy = pi[1]-pj[1], dz = pi[2]-pj[2];
    float d2 = dx*dx + dy*dy + dz*dz;
    dist_lds[tid] = d2 > 0.f ? sqrtf(d2) : 0.f;
  }

  f32x4 acc[4][8];
  #pragma unroll
  for (int nt = 0; nt < 4; ++nt)
    #pragma unroll
    for (int t = 0; t < 8; ++t) { acc[nt][t].x=0.f; acc[nt][t].y=0.f; acc[nt][t].z=0.f; acc[nt][t].w=0.f; }

  __syncthreads();     // g/dist visible; stage(0) DMA drained (vmcnt0 in barrier)
  build_af(0);         // wave-local; MFMA(0) may follow without barrier

  #pragma unroll
  for (int kk = 0; kk < 9; ++kk) {
    if (kk < 8) stage(kk + 1);            // DMA overlaps MFMA + build
    // ---- MFMA chunk kk
    {
      const char* bp = u.slabs[kk & 1];
      const char* ap = af_lds[kk & 1];
      short8 afr[4];
      #pragma unroll
      for (int nt = 0; nt < 4; ++nt)
        afr[nt] = *reinterpret_cast<const short8*>(&ap[((wn*4 + nt)*4 + hi)*256 + c15*16]);
      #pragma unroll
      for (int t = 0; t < 8; ++t) {
        if (t < tcnt) {                   // wave-uniform guard
          int tile = wj + 2*t;
          short8 bb = *reinterpret_cast<const short8*>(&bp[tile*1024 + lane*16]);
          acc[0][t] = __builtin_amdgcn_mfma_f32_16x16x32_bf16(afr[0], bb, acc[0][t], 0, 0, 0);
          acc[1][t] = __builtin_amdgcn_mfma_f32_16x16x32_bf16(afr[1], bb, acc[1][t], 0, 0, 0);
          acc[2][t] = __builtin_amdgcn_mfma_f32_16x16x32_bf16(afr[2], bb, acc[2][t], 0, 0, 0);
          acc[3][t] = __builtin_amdgcn_mfma_f32_16x16x32_bf16(afr[3], bb, acc[3][t], 0, 0, 0);
        }
      }
    }
    if (kk < 8) build_af(kk + 1);         // wave-local, fills DMA-wait window
    __syncthreads();   // drains stage(kk+1); releases slabs[kk&1] for stage(kk+2)
  }

  __builtin_amdgcn_sched_barrier(0);   // keep epilogue loads OUT of the K-loop region

  // ---- epilogue: z = acc + dist*w30 + b3 ; relu ; second layer (256 -> 4)
  float b3v[4][4], w30v[4][4]; float4 w4v[4][4];
  #pragma unroll
  for (int nt = 0; nt < 4; ++nt)
    #pragma unroll
    for (int r = 0; r < 4; ++r) {
      int n = wn*64 + nt*16 + hi*4 + r;
      b3v[nt][r]  = b3[n];
      w30v[nt][r] = W3[n];                 // W3 row 0 = dist weights
      w4v[nt][r]  = *reinterpret_cast<const float4*>(&W4[n*4]);
    }
  #pragma unroll
  for (int t = 0; t < 8; ++t) {
    if (t < tcnt) {
      int j = (jt0 + wj + 2*t)*16 + c15;
      float d = dist_lds[j];
      float4 pe; pe.x=0.f; pe.y=0.f; pe.z=0.f; pe.w=0.f;
      #pragma unroll
      for (int nt = 0; nt < 4; ++nt)
        #pragma unroll
        for (int r = 0; r < 4; ++r) {
          float z  = acc[nt][t][r] + d*w30v[nt][r] + b3v[nt][r];
          float rz = fmaxf(z, 0.f);
          pe.x += rz*w4v[nt][r].x; pe.y += rz*w4v[nt][r].y;
          pe.z += rz*w4v[nt][r].z; pe.w += rz*w4v[nt][r].w;
        }
      pe.x += __shfl_xor(pe.x, 16); pe.y += __shfl_xor(pe.y, 16);
      pe.z += __shfl_xor(pe.z, 16); pe.w += __shfl_xor(pe.w, 16);
      pe.x += __shfl_xor(pe.x, 32); pe.y += __shfl_xor(pe.y, 32);
      pe.z += __shfl_xor(pe.z, 32); pe.w += __shfl_xor(pe.w, 32);
      if (hi == 0) *reinterpret_cast<float4*>(&u.partial[wn][j][0]) = pe;
    }
  }
  __syncthreads();
  #pragma unroll
  for (int rep = 0; rep < 2; ++rep) {
    int o = rep*512 + tid;
    int j = o >> 2, e = o & 3;
    if (j >= jt0*16) {
      float v = u.partial[0][j][e] + u.partial[1][j][e]
              + u.partial[2][j][e] + u.partial[3][j][e] + b4[e];
      if (j >= i) out[((size_t)rowbase*256 + j)*NE + e] = v;            // upper+diag
      if (j > i)  out[((size_t)(bbase + j)*256 + i)*NE + e] = v;        // mirror
    }
  }
}

extern "C" void kernel_launch(void* const* d_in, const int* in_sizes, int n_in,
                              void* d_out, int out_size, void* d_ws, size_t ws_size,
                              hipStream_t stream) {
  const float* latent    = (const float*)d_in[0];
  const float* positions = (const float*)d_in[1];
  const float* atoms     = (const float*)d_in[2];
  const float* W1 = (const float*)d_in[3];
  const float* b1 = (const float*)d_in[4];
  const float* W2 = (const float*)d_in[5];
  const float* b2 = (const float*)d_in[6];
  const float* W3 = (const float*)d_in[7];
  const float* b3 = (const float*)d_in[8];
  const float* W4 = (const float*)d_in[9];
  const float* b4 = (const float*)d_in[10];
  float* out = (float*)d_out;

  char* ws = (char*)d_ws;
  float*  h_ws   = (float*)ws;                          // 8*256*256*4   = 2,097,152 B
  ushort* G_ws   = (ushort*)(ws + 2097152);             // 8*256*288*2   = 1,179,648 B
  ushort* W3T_ws = (ushort*)(ws + 2097152 + 1179648);   // 256*288*2     =   147,456 B

  hipLaunchKernelGGL(prep_h_kernel, dim3(256), dim3(256), 0, stream,
                     latent, atoms, W1, b1, W2, b2, h_ws, G_ws);
  hipLaunchKernelGGL(prep_w3t_kernel, dim3(256), dim3(256), 0, stream, W3, W3T_ws);
  hipLaunchKernelGGL(edge_main_kernel, dim3(2048), dim3(512), 0, stream,
                     positions, atoms, W3, b3, W4, b4, h_ws, G_ws, W3T_ws, out);
}

// Round 13
// 109.805 us; speedup vs baseline: 1.4725x; 1.4544x over previous
//
#include <hip/hip_runtime.h>

#define DIM 256
#define NA 16
#define NE 4
#define KTOT 288   // 16 atoms + 256 latent + 16 zero pad

typedef __attribute__((ext_vector_type(8))) short short8;
typedef __attribute__((ext_vector_type(4))) float f32x4;

static __device__ __forceinline__ ushort f2bf(float f) {
  union { float f; unsigned int u; } v; v.f = f;
  unsigned int r = (v.u + 0x7FFFu + ((v.u >> 16) & 1u)) >> 16;
  return (ushort)r;
}

static __device__ __forceinline__ float bf2f(ushort s) {
  union { unsigned int u; float f; } v; v.u = ((unsigned int)s) << 16;
  return v.f;
}

static __device__ __forceinline__ unsigned cvtpk(float lo, float hi) {
  unsigned r;
  asm("v_cvt_pk_bf16_f32 %0, %1, %2" : "=v"(r) : "v"(lo), "v"(hi));
  return r;
}

// async global->LDS DMA, 16B per lane; lds dest wave-uniform (HW adds lane*16)
static __device__ __forceinline__ void gll16(const void* g, void* l) {
  __builtin_amdgcn_global_load_lds((const __attribute__((address_space(1))) void*)g,
                                   (__attribute__((address_space(3))) void*)l, 16, 0, 0);
}

// ---------------- prep 1: h = relu(latent@W1+b1)@W2+b2 ; build G = [atoms|h|0] bf16
__global__ __launch_bounds__(256) void prep_h_kernel(
    const float* __restrict__ latent, const float* __restrict__ atoms,
    const float* __restrict__ W1, const float* __restrict__ b1,
    const float* __restrict__ W2, const float* __restrict__ b2,
    float* __restrict__ h_out, ushort* __restrict__ G_out) {
  __shared__ float lat[8][DIM];
  __shared__ float t1[8][DIM];
  const int b = blockIdx.x >> 5, i0 = (blockIdx.x & 31) * 8;
  const int k = threadIdx.x;
  #pragma unroll
  for (int r = 0; r < 8; ++r) lat[r][k] = latent[(b*256 + i0 + r) * DIM + k];
  __syncthreads();
  float acc[8];
  #pragma unroll
  for (int r = 0; r < 8; ++r) acc[r] = b1[k];
  for (int c = 0; c < DIM; c += 4) {
    float w0 = W1[(c+0)*DIM + k], w1 = W1[(c+1)*DIM + k];
    float w2 = W1[(c+2)*DIM + k], w3 = W1[(c+3)*DIM + k];
    #pragma unroll
    for (int r = 0; r < 8; ++r) {
      const float4 l4 = *reinterpret_cast<const float4*>(&lat[r][c]);
      acc[r] += l4.x*w0 + l4.y*w1 + l4.z*w2 + l4.w*w3;
    }
  }
  #pragma unroll
  for (int r = 0; r < 8; ++r) t1[r][k] = fmaxf(acc[r], 0.f);
  __syncthreads();
  #pragma unroll
  for (int r = 0; r < 8; ++r) acc[r] = b2[k];
  for (int c = 0; c < DIM; c += 4) {
    float w0 = W2[(c+0)*DIM + k], w1 = W2[(c+1)*DIM + k];
    float w2 = W2[(c+2)*DIM + k], w3 = W2[(c+3)*DIM + k];
    #pragma unroll
    for (int r = 0; r < 8; ++r) {
      const float4 l4 = *reinterpret_cast<const float4*>(&t1[r][c]);
      acc[r] += l4.x*w0 + l4.y*w1 + l4.z*w2 + l4.w*w3;
    }
  }
  #pragma unroll
  for (int r = 0; r < 8; ++r) {
    int row = b*256 + i0 + r;
    h_out[row*DIM + k] = acc[r];
    G_out[row*KTOT + NA + k] = f2bf(acc[r]);
  }
  if (k < NA) {
    #pragma unroll
    for (int r = 0; r < 8; ++r) {
      int row = b*256 + i0 + r;
      G_out[row*KTOT + k] = f2bf(atoms[row*NA + k]);
      G_out[row*KTOT + 272 + k] = 0;
    }
  }
}

// ---------------- prep 2: W3T[n][c] = bf16(W3[1+c][n]) zero-padded to 288
__global__ __launch_bounds__(256) void prep_w3t_kernel(
    const float* __restrict__ W3, ushort* __restrict__ W3T) {
  const int kk = blockIdx.x, c = threadIdx.x;
  W3T[kk*KTOT + c] = (c < 272) ? f2bf(W3[(1+c)*DIM + kk]) : (ushort)0;
  if (c < 32) {
    int c2 = 256 + c;
    W3T[kk*KTOT + c2] = (c2 < 272) ? f2bf(W3[(1+c2)*DIM + kk]) : (ushort)0;
  }
}

// ---------------- main: one WG per (b, it<=jt) pair-tile (8*136 = 1088 WGs).
// Dense 256-pair x 256-n x K288 MFMA tile per WG:
//   A = W3T (rows=n, raw DMA, zero VALU), B = y[pair][c]=G[i][c]*G[j][c]
//   (built cooperatively, 16 elems/thread/chunk). D: row=n, col=pair.
// Mirror-write fills the jt>it transpose; diagonal tiles are self-contained.
__global__ __attribute__((amdgpu_flat_work_group_size(512,512), amdgpu_waves_per_eu(2,2)))
void edge_main_kernel(
    const float* __restrict__ positions,
    const float* __restrict__ W3, const float* __restrict__ b3,
    const float* __restrict__ W4, const float* __restrict__ b4,
    const ushort* __restrict__ G, const ushort* __restrict__ W3T,
    float* __restrict__ out) {
  __shared__ union UU {
    char w3t[2][16384];           // A-operand chunk dbuf (16 ntiles x 1KB)
    float partial[4][256][4];     // epilogue partials (16KB), after final barrier
  } u;
  __shared__ char y_lds[2][16384];   // B-operand chunk dbuf (16 ptiles x 1KB)
  __shared__ float dist_lds[256];

  const int bid = blockIdx.x;
  const int b = bid / 136;
  int q = bid - b*136;
  int it = 0;
  while (q >= 16 - it) { q -= 16 - it; ++it; }
  const int jt = it + q;
  const int i0 = b*256 + it*16, j0 = b*256 + jt*16;   // global row bases

  const int tid = threadIdx.x;
  const int lane = tid & 63, w = tid >> 6;
  const int wn = w & 3;      // n-group: ntiles wn*4 .. +4
  const int wp = w >> 2;     // pair-group: pairs wp*128 .. +128
  const int c15 = lane & 15, hi = lane >> 4;

  // ---- prologue: dist for all 256 pairs of this tile
  if (tid < 256) {
    int pi = tid >> 4, pj = tid & 15;
    const float* pa = &positions[(i0 + pi)*3];
    const float* pb = &positions[(j0 + pj)*3];
    float dx = pa[0]-pb[0], dy = pa[1]-pb[1], dz = pa[2]-pb[2];
    float d2 = dx*dx + dy*dy + dz*dz;
    dist_lds[tid] = d2 > 0.f ? sqrtf(d2) : 0.f;
  }

  // ---- stage W3T chunk kk (16KB): subtile(nt_,oct) at (nt_*4+oct)*256
  auto stage = [&](int kk) {
    #pragma unroll
    for (int qq = 0; qq < 2; ++qq) {
      int s0 = w*8 + qq*4;                  // wave-uniform base subtile
      int sub = s0 + hi;
      int nt_ = sub >> 2, oct = sub & 3;
      const ushort* src = &W3T[(size_t)(nt_*16 + c15)*KTOT + kk*32 + oct*8];
      gll16(src, u.w3t[kk & 1] + s0*256);   // + lane*16 implicit
    }
  };

  // ---- y-build: thread owns (pair = tid>>1, octet-pair po = tid&1)
  const int pair_ = tid >> 1, po = tid & 1;
  const int pi_ = pair_ >> 4, pj_ = pair_ & 15;
  const ushort* giBase = &G[(size_t)(i0 + pi_)*KTOT + po*16];
  const ushort* gjBase = &G[(size_t)(j0 + pj_)*KTOT + po*16];

  short8 yi0, yi1, yj0, yj1;
  auto y_load = [&](int kk) {               // issue early (T14 split)
    yi0 = *reinterpret_cast<const short8*>(giBase + kk*32);
    yi1 = *reinterpret_cast<const short8*>(giBase + kk*32 + 8);
    yj0 = *reinterpret_cast<const short8*>(gjBase + kk*32);
    yj1 = *reinterpret_cast<const short8*>(gjBase + kk*32 + 8);
  };
  auto y_finish = [&](int kk) {             // mul + pack + 2x ds_write_b128
    union { ushort us[8]; short8 s8; } A0, A1, B0, B1;
    A0.s8 = yi0; A1.s8 = yi1; B0.s8 = yj0; B1.s8 = yj1;
    uint4 p0, p1;
    p0.x = cvtpk(bf2f(A0.us[0])*bf2f(B0.us[0]), bf2f(A0.us[1])*bf2f(B0.us[1]));
    p0.y = cvtpk(bf2f(A0.us[2])*bf2f(B0.us[2]), bf2f(A0.us[3])*bf2f(B0.us[3]));
    p0.z = cvtpk(bf2f(A0.us[4])*bf2f(B0.us[4]), bf2f(A0.us[5])*bf2f(B0.us[5]));
    p0.w = cvtpk(bf2f(A0.us[6])*bf2f(B0.us[6]), bf2f(A0.us[7])*bf2f(B0.us[7]));
    p1.x = cvtpk(bf2f(A1.us[0])*bf2f(B1.us[0]), bf2f(A1.us[1])*bf2f(B1.us[1]));
    p1.y = cvtpk(bf2f(A1.us[2])*bf2f(B1.us[2]), bf2f(A1.us[3])*bf2f(B1.us[3]));
    p1.z = cvtpk(bf2f(A1.us[4])*bf2f(B1.us[4]), bf2f(A1.us[5])*bf2f(B1.us[5]));
    p1.w = cvtpk(bf2f(A1.us[6])*bf2f(B1.us[6]), bf2f(A1.us[7])*bf2f(B1.us[7]));
    char* dst = y_lds[kk & 1] + pi_*1024 + po*512 + pj_*16;
    *reinterpret_cast<uint4*>(dst) = p0;
    *reinterpret_cast<uint4*>(dst + 256) = p1;
  };

  f32x4 acc[4][8];
  #pragma unroll
  for (int at = 0; at < 4; ++at)
    #pragma unroll
    for (int bt = 0; bt < 8; ++bt) { acc[at][bt].x=0.f; acc[at][bt].y=0.f; acc[at][bt].z=0.f; acc[at][bt].w=0.f; }

  stage(0);
  y_load(0);
  y_finish(0);
  __syncthreads();   // stage(0) DMA drained; y(0) + dist visible

  #pragma unroll
  for (int kk = 0; kk < 9; ++kk) {
    if (kk < 8) { y_load(kk + 1); stage(kk + 1); }     // into opposite buffers
    // ---- MFMA chunk kk: 4 A-frags + 8 B-frags, 32 MFMA
    {
      const char* ap = u.w3t[kk & 1];
      const char* bp = y_lds[kk & 1];
      short8 afr[4];
      #pragma unroll
      for (int at = 0; at < 4; ++at)
        afr[at] = *reinterpret_cast<const short8*>(ap + (wn*4 + at)*1024 + lane*16);
      #pragma unroll
      for (int bt = 0; bt < 8; ++bt) {
        short8 bb = *reinterpret_cast<const short8*>(bp + (wp*8 + bt)*1024 + lane*16);
        acc[0][bt] = __builtin_amdgcn_mfma_f32_16x16x32_bf16(afr[0], bb, acc[0][bt], 0, 0, 0);
        acc[1][bt] = __builtin_amdgcn_mfma_f32_16x16x32_bf16(afr[1], bb, acc[1][bt], 0, 0, 0);
        acc[2][bt] = __builtin_amdgcn_mfma_f32_16x16x32_bf16(afr[2], bb, acc[2][bt], 0, 0, 0);
        acc[3][bt] = __builtin_amdgcn_mfma_f32_16x16x32_bf16(afr[3], bb, acc[3][bt], 0, 0, 0);
      }
    }
    if (kk < 8) y_finish(kk + 1);                      // writes other y buffer
    __syncthreads();   // drains stage DMA; y writes visible; frees kk bufs
  }

  __builtin_amdgcn_sched_barrier(0);   // keep epilogue loads out of K-loop region

  // ---- epilogue: z = acc + dist*w30 + b3 ; relu ; x W4 (256n -> 4)
  float b3v[4][4], w30v[4][4]; float4 w4v[4][4];
  #pragma unroll
  for (int at = 0; at < 4; ++at)
    #pragma unroll
    for (int r = 0; r < 4; ++r) {
      int n = (wn*4 + at)*16 + hi*4 + r;
      b3v[at][r]  = b3[n];
      w30v[at][r] = W3[n];                 // W3 row 0 = dist weights
      w4v[at][r]  = *reinterpret_cast<const float4*>(&W4[n*4]);
    }
  #pragma unroll
  for (int bt = 0; bt < 8; ++bt) {
    int pair = wp*128 + bt*16 + c15;
    float d = dist_lds[pair];
    float4 pe; pe.x=0.f; pe.y=0.f; pe.z=0.f; pe.w=0.f;
    #pragma unroll
    for (int at = 0; at < 4; ++at)
      #pragma unroll
      for (int r = 0; r < 4; ++r) {
        float z  = acc[at][bt][r] + d*w30v[at][r] + b3v[at][r];
        float rz = fmaxf(z, 0.f);
        pe.x += rz*w4v[at][r].x; pe.y += rz*w4v[at][r].y;
        pe.z += rz*w4v[at][r].z; pe.w += rz*w4v[at][r].w;
      }
    // reduce over hi (n-quarters): lanes differ only in hi for fixed c15
    pe.x += __shfl_xor(pe.x, 16); pe.y += __shfl_xor(pe.y, 16);
    pe.z += __shfl_xor(pe.z, 16); pe.w += __shfl_xor(pe.w, 16);
    pe.x += __shfl_xor(pe.x, 32); pe.y += __shfl_xor(pe.y, 32);
    pe.z += __shfl_xor(pe.z, 32); pe.w += __shfl_xor(pe.w, 32);
    if (hi == 0) *reinterpret_cast<float4*>(&u.partial[wn][pair][0]) = pe;
  }
  __syncthreads();
  if (tid < 256) {
    int pair = tid;
    float4 v;
    v.x = u.partial[0][pair][0] + u.partial[1][pair][0] + u.partial[2][pair][0] + u.partial[3][pair][0];
    v.y = u.partial[0][pair][1] + u.partial[1][pair][1] + u.partial[2][pair][1] + u.partial[3][pair][1];
    v.z = u.partial[0][pair][2] + u.partial[1][pair][2] + u.partial[2][pair][2] + u.partial[3][pair][2];
    v.w = u.partial[0][pair][3] + u.partial[1][pair][3] + u.partial[2][pair][3] + u.partial[3][pair][3];
    const float4 bv = *reinterpret_cast<const float4*>(b4);
    v.x += bv.x; v.y += bv.y; v.z += bv.z; v.w += bv.w;
    int il = it*16 + (pair >> 4);       // local i row
    int jl = jt*16 + (pair & 15);       // local j row
    *reinterpret_cast<float4*>(&out[(((size_t)b*256 + il)*256 + jl)*NE]) = v;
    if (it != jt)
      *reinterpret_cast<float4*>(&out[(((size_t)b*256 + jl)*256 + il)*NE]) = v;
  }
}

extern "C" void kernel_launch(void* const* d_in, const int* in_sizes, int n_in,
                              void* d_out, int out_size, void* d_ws, size_t ws_size,
                              hipStream_t stream) {
  const float* latent    = (const float*)d_in[0];
  const float* positions = (const float*)d_in[1];
  const float* atoms     = (const float*)d_in[2];
  const float* W1 = (const float*)d_in[3];
  const float* b1 = (const float*)d_in[4];
  const float* W2 = (const float*)d_in[5];
  const float* b2 = (const float*)d_in[6];
  const float* W3 = (const float*)d_in[7];
  const float* b3 = (const float*)d_in[8];
  const float* W4 = (const float*)d_in[9];
  const float* b4 = (const float*)d_in[10];
  float* out = (float*)d_out;

  char* ws = (char*)d_ws;
  float*  h_ws   = (float*)ws;                          // 8*256*256*4   = 2,097,152 B
  ushort* G_ws   = (ushort*)(ws + 2097152);             // 8*256*288*2   = 1,179,648 B
  ushort* W3T_ws = (ushort*)(ws + 2097152 + 1179648);   // 256*288*2     =   147,456 B

  hipLaunchKernelGGL(prep_h_kernel, dim3(256), dim3(256), 0, stream,
                     latent, atoms, W1, b1, W2, b2, h_ws, G_ws);
  hipLaunchKernelGGL(prep_w3t_kernel, dim3(256), dim3(256), 0, stream, W3, W3T_ws);
  hipLaunchKernelGGL(edge_main_kernel, dim3(1088), dim3(512), 0, stream,
                     positions, W3, b3, W4, b4, G_ws, W3T_ws, out);
}